// Round 10
// baseline (8683.212 us; speedup 1.0000x reference)
//
#include <hip/hip_runtime.h>
#include <math.h>

typedef __attribute__((ext_vector_type(4))) float f32x4;
typedef __attribute__((ext_vector_type(8))) short bf16x8;

#define DI __device__ __forceinline__

DI unsigned short f32_to_bf16(float f) {
  unsigned int u = __float_as_uint(f);
  u += 0x7FFFu + ((u >> 16) & 1u);   // round-to-nearest-even
  return (unsigned short)(u >> 16);
}

static constexpr float kCode[16] = {
    -1.0f, -0.6961928009986877f, -0.5250730514526367f, -0.39491748809814453f,
    -0.28444138169288635f, -0.18477343022823334f, -0.09105003625154495f, 0.0f,
    0.07958029955625534f, 0.16093020141124725f, 0.24611230194568634f,
    0.33791524171829224f, 0.44070982933044434f, 0.5626170039176941f,
    0.7229568362236023f, 1.0f};

// ---------------------------------------------------------------------------
// NF4 quant-dequant (block=64): 16 lanes/block, float4/lane. Division-free.
// ---------------------------------------------------------------------------
DI void dequant_body(const float* __restrict__ in, unsigned short* __restrict__ out, int i) {
  f32x4 v = reinterpret_cast<const f32x4*>(in)[i];
  float am = fmaxf(fmaxf(fabsf(v.x), fabsf(v.y)), fmaxf(fabsf(v.z), fabsf(v.w)));
  am = fmaxf(am, __shfl_xor(am, 1));
  am = fmaxf(am, __shfl_xor(am, 2));
  am = fmaxf(am, __shfl_xor(am, 4));
  am = fmaxf(am, __shfl_xor(am, 8));
  const float scale = (am == 0.0f) ? 1.0f : am;
  float sb[15];
#pragma unroll
  for (int b = 0; b < 15; ++b)
    sb[b] = (0.5f * (kCode[b] + kCode[b + 1])) * scale;
  unsigned short o[4];
#pragma unroll
  for (int j = 0; j < 4; ++j) {
    const float vj = ((const float*)&v)[j];
    int idx = 0;
#pragma unroll
    for (int b = 0; b < 15; ++b)
      idx += (vj > sb[b]) ? 1 : 0;
    o[j] = f32_to_bf16(kCode[idx] * am);
  }
  reinterpret_cast<ushort4*>(out)[i] = make_ushort4(o[0], o[1], o[2], o[3]);
}

__global__ void __launch_bounds__(256) k_dequant_nf4(
    const float* __restrict__ in, unsigned short* __restrict__ out, int n4) {
  int i = blockIdx.x * 256 + threadIdx.x;
  if (i >= n4) return;
  dequant_body(in, out, i);
}

__global__ void __launch_bounds__(256) k_dequant_nf4_2(
    const float* __restrict__ in1, const float* __restrict__ in2,
    unsigned short* __restrict__ out1, unsigned short* __restrict__ out2, int n4) {
  int i = blockIdx.x * 256 + threadIdx.x;
  if (i < n4) {
    dequant_body(in1, out1, i);
  } else {
    dequant_body(in2, out2, i - n4);
  }
}

__global__ void __launch_bounds__(256) k_f32_to_bf16(
    const float* __restrict__ in, unsigned short* __restrict__ out, int n4) {
  int i = blockIdx.x * 256 + threadIdx.x;
  if (i >= n4) return;
  f32x4 v = reinterpret_cast<const f32x4*>(in)[i];
  reinterpret_cast<ushort4*>(out)[i] =
      make_ushort4(f32_to_bf16(v.x), f32_to_bf16(v.y), f32_to_bf16(v.z), f32_to_bf16(v.w));
}

// ---------------------------------------------------------------------------
// GEMM helpers. BK=32, LDS rows = 64B. Element (r,k) at byte
//   r*64 + (((k>>3) ^ ((r>>1)&3))<<4) + (k&7)*2     (round-4 verified)
// Staging: global_load_lds linear; lane l of 1KB unit covers row 16u+(l>>2),
// k-chunk (l&3)^((l>>3)&3). Read: (rowbase+(l&15))*64 + ((l>>4)^((l>>1)&3))<<4
// -> conflict-free (SQ_LDS_BANK_CONFLICT == 0, rounds 4/5/8/9).
// ---------------------------------------------------------------------------
DI void gload16(const void* g, void* l) {
  __builtin_amdgcn_global_load_lds(
      (const __attribute__((address_space(1))) void*)g,
      (__attribute__((address_space(3))) void*)l, 16, 0, 0);
}

DI void barrier_nodrain() {
  asm volatile("" ::: "memory");
  __builtin_amdgcn_s_barrier();
  asm volatile("" ::: "memory");
}

#define WAITV(N) asm volatile("s_waitcnt vmcnt(" #N ")" ::: "memory")

DI float fast_silu(float g) {
  const float e = __builtin_amdgcn_exp2f(g * -1.442695041f);
  return g * __builtin_amdgcn_rcpf(1.0f + e);
}

// ---------------------------------------------------------------------------
// Fused dual GEMM + SwiGLU. BM=256, BN=256, BK=32, 16 waves (4/SIMD):
// waves 0-7 gate (B1), 8-15 up (B2); pair p=w&7 owns 128x64 at
// (wr=p>>2, wc=p&3). Per wave: 8 A-frags + 4 B-frags, 32 MFMA/K-step.
// LDS: 3 bufs x 48KB (A 16K | B1 16K | B2 16K) = 144 KiB; prefetch-2,
// counted WAITV(3). nt-major XCD swizzle (688 = 8 x 86).
// Epilogue: 2-round pairwise exchange (8KB/wave/round = 128KB).
// ---------------------------------------------------------------------------
__global__ void __launch_bounds__(1024, 2) k_gemm_dual_swiglu(
    const unsigned short* __restrict__ X,
    const unsigned short* __restrict__ W1,
    const unsigned short* __restrict__ W2,
    unsigned short* __restrict__ H) {
  constexpr int K = 4096, N = 11008, NK = K / 32;
  __shared__ char ldsb[147456];

  const int tid = threadIdx.x;
  const int w = tid >> 6, l = tid & 63;

  // nt-major XCD swizzle: 688 blocks = 8 XCD x 86; bijective.
  const int bid = blockIdx.x;
  const int xcd = bid & 7, ii = bid >> 3;   // ii in [0,86)
  const int nt = ii >> 1;                   // 0..42  (weight panel, slow)
  const int mt = xcd * 2 + (ii & 1);        // 0..15  (X panel, 2 per XCD)
  const int m0 = mt * 256, n0 = nt * 256;

  const int p = w & 7;
  const bool isGate = (w < 8);
  const int wr = p >> 2, wc = p & 3;

  // ---- staging: 48 1KB-units, 3 per wave ----
  const int lrow = l >> 2;                              // 0..15
  const int kc8 = (((l & 3) ^ ((l >> 3) & 3)) << 3);    // elem col 0,8,16,24
  const unsigned short* pgA  = X  + (size_t)(m0 + 16 * w + lrow) * K + kc8;
  const unsigned short* pgB1 = W1 + (size_t)(n0 + 16 * w + lrow) * K + kc8;
  const unsigned short* pgB2 = W2 + (size_t)(n0 + 16 * w + lrow) * K + kc8;
  const int ldA = w * 1024, ldB1 = 16384 + w * 1024, ldB2 = 32768 + w * 1024;

  // ---- read bases ----
  const int roff = (((l >> 4) ^ ((l >> 1) & 3)) << 4);
  const char* rdA = ldsb + (wr * 128 + (l & 15)) * 64 + roff;
  const char* rdB = ldsb + 16384 + (isGate ? 0 : 16384) +
                    (wc * 64 + (l & 15)) * 64 + roff;

  f32x4 acc[8][4] = {};

#define TILE_BODY(bo) {                                                        \
  bf16x8 a[8], b[4];                                                           \
  _Pragma("unroll") for (int m = 0; m < 8; ++m)                                \
    a[m] = *(const bf16x8*)(rdA + (bo) + m * 1024);                            \
  _Pragma("unroll") for (int n = 0; n < 4; ++n)                                \
    b[n] = *(const bf16x8*)(rdB + (bo) + n * 1024);                            \
  __builtin_amdgcn_s_setprio(1);                                               \
  _Pragma("unroll") for (int m = 0; m < 8; ++m)                                \
    _Pragma("unroll") for (int n = 0; n < 4; ++n)                              \
      acc[m][n] = __builtin_amdgcn_mfma_f32_16x16x32_bf16(a[m], b[n], acc[m][n], 0, 0, 0); \
  __builtin_amdgcn_s_setprio(0); }

  // prologue: stage tiles 0 (buf0), 1 (buf1)
  gload16(pgA, ldsb + ldA);            gload16(pgB1, ldsb + ldB1);
  gload16(pgB2, ldsb + ldB2);
  gload16(pgA + 32, ldsb + 49152 + ldA);  gload16(pgB1 + 32, ldsb + 49152 + ldB1);
  gload16(pgB2 + 32, ldsb + 49152 + ldB2);
  pgA += 64; pgB1 += 64; pgB2 += 64;
  WAITV(3);
  barrier_nodrain();

  int bo_cur = 0, bo_stg = 98304;      // read buf, stage buf (t+2)
  for (int t = 0; t + 2 < NK; ++t) {
    gload16(pgA, ldsb + bo_stg + ldA);
    gload16(pgB1, ldsb + bo_stg + ldB1);
    gload16(pgB2, ldsb + bo_stg + ldB2);
    pgA += 32; pgB1 += 32; pgB2 += 32;
    TILE_BODY(bo_cur);
    WAITV(3); barrier_nodrain();
    bo_cur = (bo_cur == 98304) ? 0 : bo_cur + 49152;
    bo_stg = (bo_stg == 98304) ? 0 : bo_stg + 49152;
  }
  TILE_BODY(bo_cur); WAITV(0); barrier_nodrain();
  bo_cur = (bo_cur == 98304) ? 0 : bo_cur + 49152;
  TILE_BODY(bo_cur);
#undef TILE_BODY

  // ---- epilogue: 2-round pairwise exchange (m-split), SwiGLU, store ----
  // gate stores m 0-3 (needs up's acc[0-3]); up stores m 4-7 (needs gate's).
  const int er = (l >> 4) * 4, ec = l & 15;
  char* myx = ldsb + w * 8192;
  const char* px = ldsb + (w ^ 8) * 8192;
#pragma unroll
  for (int r = 0; r < 2; ++r) {
    barrier_nodrain();   // LDS region free (staging dead / prev round done)
#pragma unroll
    for (int m2 = 0; m2 < 2; ++m2)
#pragma unroll
      for (int n = 0; n < 4; ++n) {
        const int ms = (isGate ? 4 : 0) + r * 2 + m2;   // frag partner needs
        *(f32x4*)(myx + ((m2 * 4 + n) * 64 + l) * 16) = acc[ms][n];
      }
    barrier_nodrain();
#pragma unroll
    for (int m2 = 0; m2 < 2; ++m2)
#pragma unroll
      for (int n = 0; n < 4; ++n) {
        const int mk = (isGate ? 0 : 4) + r * 2 + m2;   // rows this wave stores
        f32x4 other = *(const f32x4*)(px + ((m2 * 4 + n) * 64 + l) * 16);
#pragma unroll
        for (int j = 0; j < 4; ++j) {
          const float g_ = isGate ? acc[mk][n][j] : other[j];
          const float u_ = isGate ? other[j] : acc[mk][n][j];
          const float s = fast_silu(g_);
          const int row = m0 + wr * 128 + mk * 16 + er + j;
          const int col = n0 + wc * 64 + n * 16 + ec;
          H[(size_t)row * N + col] = f32_to_bf16(s * u_);
        }
      }
  }
}

// ---------------------------------------------------------------------------
// Output GEMM. BM=BN=256, BK=32, 16 waves (4M x 4N), per-wave 64x64.
// 4 LDS bufs x 32KB (A 16K | B 16K), prefetch 3, hoisted ladder,
// pointer-increment staging. nt-major XCD swizzle. (round-9 proven)
// ---------------------------------------------------------------------------
__global__ void __launch_bounds__(1024, 4) k_gemm_out(
    const unsigned short* __restrict__ Hm,
    const unsigned short* __restrict__ W3,
    float* __restrict__ Out) {
  constexpr int K = 11008, N = 4096, NK = K / 32;   // NK = 344
  __shared__ char ldsb[131072];

  const int tid = threadIdx.x;
  const int w = tid >> 6, l = tid & 63;

  const int bid = blockIdx.x;
  const int xcd = bid & 7, ii = bid >> 3;   // ii in [0,32)
  const int nt = ii >> 1;                   // 0..15
  const int mt = xcd * 2 + (ii & 1);        // 0..15
  const int m0 = mt * 256, n0 = nt * 256;

  const int wr = w >> 2, wc = w & 3;

  const int lrow = l >> 2;
  const int kc8 = (((l & 3) ^ ((l >> 3) & 3)) << 3);
  const unsigned short* gsrc0;
  const unsigned short* gsrc1;
  int ldst0;
  if (w < 8) {          // A units
    gsrc0 = Hm + (size_t)(m0 + 32 * w + lrow) * K + kc8;
    gsrc1 = Hm + (size_t)(m0 + 32 * w + 16 + lrow) * K + kc8;
    ldst0 = 2 * w * 1024;
  } else {              // B units
    gsrc0 = W3 + (size_t)(n0 + 32 * (w - 8) + lrow) * K + kc8;
    gsrc1 = W3 + (size_t)(n0 + 32 * (w - 8) + 16 + lrow) * K + kc8;
    ldst0 = 16384 + (w - 8) * 2048;
  }

  const int roff = (((l >> 4) ^ ((l >> 1) & 3)) << 4);
  const char* rdA = ldsb + (wr * 64 + (l & 15)) * 64 + roff;
  const char* rdB = ldsb + 16384 + (wc * 64 + (l & 15)) * 64 + roff;

  f32x4 acc[4][4] = {};

#define TILE_BODY(bo) {                                                        \
  bf16x8 a[4], b[4];                                                           \
  _Pragma("unroll") for (int m = 0; m < 4; ++m)                                \
    a[m] = *(const bf16x8*)(rdA + (bo) + m * 1024);                            \
  _Pragma("unroll") for (int n = 0; n < 4; ++n)                                \
    b[n] = *(const bf16x8*)(rdB + (bo) + n * 1024);                            \
  __builtin_amdgcn_s_setprio(1);                                               \
  _Pragma("unroll") for (int m = 0; m < 4; ++m)                                \
    _Pragma("unroll") for (int n = 0; n < 4; ++n)                              \
      acc[m][n] = __builtin_amdgcn_mfma_f32_16x16x32_bf16(a[m], b[n], acc[m][n], 0, 0, 0); \
  __builtin_amdgcn_s_setprio(0); }

  gload16(gsrc0, ldsb + ldst0);               gload16(gsrc1, ldsb + ldst0 + 1024);
  gload16(gsrc0 + 32, ldsb + 32768 + ldst0);  gload16(gsrc1 + 32, ldsb + 32768 + ldst0 + 1024);
  gload16(gsrc0 + 64, ldsb + 65536 + ldst0);  gload16(gsrc1 + 64, ldsb + 65536 + ldst0 + 1024);
  const unsigned short* pg0 = gsrc0 + 96;
  const unsigned short* pg1 = gsrc1 + 96;
  WAITV(4);
  barrier_nodrain();

  int t = 0;
  for (; t + 3 < NK; ++t) {
    const int bo = (t & 3) << 15;
    const int bs = ((t + 3) & 3) << 15;
    gload16(pg0, ldsb + bs + ldst0);
    gload16(pg1, ldsb + bs + ldst0 + 1024);
    pg0 += 32; pg1 += 32;
    TILE_BODY(bo);
    WAITV(4); barrier_nodrain();
  }
  TILE_BODY((t & 3) << 15); WAITV(2); barrier_nodrain(); ++t;
  TILE_BODY((t & 3) << 15); WAITV(0); barrier_nodrain(); ++t;
  TILE_BODY((t & 3) << 15);
#undef TILE_BODY

  const int er = (l >> 4) * 4, ec = l & 15;
#pragma unroll
  for (int m = 0; m < 4; ++m)
#pragma unroll
    for (int n = 0; n < 4; ++n) {
      const int row = m0 + wr * 64 + m * 16 + er;
      const int col = n0 + wc * 64 + n * 16 + ec;
      float* ptr = Out + (size_t)row * N + col;
#pragma unroll
      for (int j = 0; j < 4; ++j) ptr[(size_t)j * N] = acc[m][n][j];
    }
}

// ---------------------------------------------------------------------------
extern "C" void kernel_launch(void* const* d_in, const int* in_sizes, int n_in,
                              void* d_out, int out_size, void* d_ws, size_t ws_size,
                              hipStream_t stream) {
  const float* x  = (const float*)d_in[0];   // [2,2048,4096] -> [4096][4096]
  const float* w1 = (const float*)d_in[1];   // [11008,4096]
  const float* w2 = (const float*)d_in[2];   // [11008,4096]
  const float* w3 = (const float*)d_in[3];   // [4096,11008]
  float* out = (float*)d_out;

  char* ws = (char*)d_ws;
  unsigned short* xb  = (unsigned short*)(ws);                // 32 MiB
  unsigned short* w1b = (unsigned short*)(ws + 33554432);     // 86 MiB
  unsigned short* w2b = (unsigned short*)(ws + 123731968);    // 86 MiB
  unsigned short* hb  = (unsigned short*)(ws + 213909504);    // 86 MiB
  unsigned short* w3b = w1b;  // reuse after gemm1 (stream-ordered)

  const int NW = 11008 * 4096 / 4;
  k_f32_to_bf16<<<16384, 256, 0, stream>>>(x, xb, 4096 * 4096 / 4);
  k_dequant_nf4_2<<<2 * (NW / 256), 256, 0, stream>>>(w1, w2, w1b, w2b, NW);

  // gate/up + SwiGLU -> h  (M=4096, N=11008, K=4096): 688 = 16mt x 43nt
  k_gemm_dual_swiglu<<<688, 1024, 0, stream>>>(xb, w1b, w2b, hb);

  k_dequant_nf4<<<NW / 256, 256, 0, stream>>>(w3, w3b, NW);

  // out = h . w3^T  (M=4096, N=4096, K=11008)
  k_gemm_out<<<256, 1024, 0, stream>>>(hb, w3b, out);
}

// Round 11
// 1250.781 us; speedup vs baseline: 6.9422x; 6.9422x over previous
//
#include <hip/hip_runtime.h>
#include <math.h>

typedef __attribute__((ext_vector_type(4))) float f32x4;
typedef __attribute__((ext_vector_type(8))) short bf16x8;

#define DI __device__ __forceinline__

DI unsigned short f32_to_bf16(float f) {
  unsigned int u = __float_as_uint(f);
  u += 0x7FFFu + ((u >> 16) & 1u);   // round-to-nearest-even
  return (unsigned short)(u >> 16);
}

static constexpr float kCode[16] = {
    -1.0f, -0.6961928009986877f, -0.5250730514526367f, -0.39491748809814453f,
    -0.28444138169288635f, -0.18477343022823334f, -0.09105003625154495f, 0.0f,
    0.07958029955625534f, 0.16093020141124725f, 0.24611230194568634f,
    0.33791524171829224f, 0.44070982933044434f, 0.5626170039176941f,
    0.7229568362236023f, 1.0f};

// ---------------------------------------------------------------------------
// NF4 quant-dequant (block=64): 16 lanes/block, float4/lane. Division-free.
// ---------------------------------------------------------------------------
DI void dequant_body(const float* __restrict__ in, unsigned short* __restrict__ out, int i) {
  f32x4 v = reinterpret_cast<const f32x4*>(in)[i];
  float am = fmaxf(fmaxf(fabsf(v.x), fabsf(v.y)), fmaxf(fabsf(v.z), fabsf(v.w)));
  am = fmaxf(am, __shfl_xor(am, 1));
  am = fmaxf(am, __shfl_xor(am, 2));
  am = fmaxf(am, __shfl_xor(am, 4));
  am = fmaxf(am, __shfl_xor(am, 8));
  const float scale = (am == 0.0f) ? 1.0f : am;
  float sb[15];
#pragma unroll
  for (int b = 0; b < 15; ++b)
    sb[b] = (0.5f * (kCode[b] + kCode[b + 1])) * scale;
  unsigned short o[4];
#pragma unroll
  for (int j = 0; j < 4; ++j) {
    const float vj = ((const float*)&v)[j];
    int idx = 0;
#pragma unroll
    for (int b = 0; b < 15; ++b)
      idx += (vj > sb[b]) ? 1 : 0;
    o[j] = f32_to_bf16(kCode[idx] * am);
  }
  reinterpret_cast<ushort4*>(out)[i] = make_ushort4(o[0], o[1], o[2], o[3]);
}

__global__ void __launch_bounds__(256) k_dequant_nf4(
    const float* __restrict__ in, unsigned short* __restrict__ out, int n4) {
  int i = blockIdx.x * 256 + threadIdx.x;
  if (i >= n4) return;
  dequant_body(in, out, i);
}

__global__ void __launch_bounds__(256) k_dequant_nf4_2(
    const float* __restrict__ in1, const float* __restrict__ in2,
    unsigned short* __restrict__ out1, unsigned short* __restrict__ out2, int n4) {
  int i = blockIdx.x * 256 + threadIdx.x;
  if (i < n4) {
    dequant_body(in1, out1, i);
  } else {
    dequant_body(in2, out2, i - n4);
  }
}

__global__ void __launch_bounds__(256) k_f32_to_bf16(
    const float* __restrict__ in, unsigned short* __restrict__ out, int n4) {
  int i = blockIdx.x * 256 + threadIdx.x;
  if (i >= n4) return;
  f32x4 v = reinterpret_cast<const f32x4*>(in)[i];
  reinterpret_cast<ushort4*>(out)[i] =
      make_ushort4(f32_to_bf16(v.x), f32_to_bf16(v.y), f32_to_bf16(v.z), f32_to_bf16(v.w));
}

// ---------------------------------------------------------------------------
// GEMM helpers. BK=32, LDS rows = 64B. Element (r,k) at byte
//   r*64 + (((k>>3) ^ ((r>>1)&3))<<4) + (k&7)*2     (round-4 verified)
// Staging: global_load_lds linear; lane l of 1KB unit covers row 16u+(l>>2),
// k-chunk (l&3)^((l>>3)&3). Read: (rowbase+(l&15))*64 + ((l>>4)^((l>>1)&3))<<4
// -> conflict-free (SQ_LDS_BANK_CONFLICT == 0, rounds 4/5/8/9).
// 5-buffer pairwise pipeline: one barrier + one WAITV per 2 K-steps.
//   invariant entering pair (t,t+1): only stage(t+2) outstanding (2 loads);
//   pair issues stage(t+3), stage(t+4); WAITV(2) -> t+2,t+3 resident for
//   next pair. stage(t+3)/(t+4) overwrite tiles t-2/t-1 (read previous pair,
//   before its barrier) -> no race.
// ---------------------------------------------------------------------------
DI void gload16(const void* g, void* l) {
  __builtin_amdgcn_global_load_lds(
      (const __attribute__((address_space(1))) void*)g,
      (__attribute__((address_space(3))) void*)l, 16, 0, 0);
}

DI void barrier_nodrain() {
  asm volatile("" ::: "memory");
  __builtin_amdgcn_s_barrier();
  asm volatile("" ::: "memory");
}

#define WAITV(N) asm volatile("s_waitcnt vmcnt(" #N ")" ::: "memory")

DI float fast_silu(float g) {
  const float e = __builtin_amdgcn_exp2f(g * -1.442695041f);
  return g * __builtin_amdgcn_rcpf(1.0f + e);
}

DI int wrap5(int x) { return x >= 163840 ? x - 163840 : x; }

// ---------------------------------------------------------------------------
// Fused dual GEMM + SwiGLU. BM=256, BN=128, BK=32, 16 waves (4/SIMD):
// waves 0-7 gate (B1), 8-15 up (B2); pair p = w&7 owns 64x64 at
// (wr=p>>1, wc=p&1). 5 LDS bufs x 32KB (A 16K | B1 8K | B2 8K) = 160 KiB,
// pairwise pipeline (1 barrier / 2 K-steps). nt-major XCD swizzle.
// ---------------------------------------------------------------------------
__global__ void __launch_bounds__(1024, 4) k_gemm_dual_swiglu(
    const unsigned short* __restrict__ X,
    const unsigned short* __restrict__ W1,
    const unsigned short* __restrict__ W2,
    unsigned short* __restrict__ H) {
  constexpr int K = 4096, N = 11008, NK = K / 32;   // NK = 128 (even)
  __shared__ char ldsb[163840];

  const int tid = threadIdx.x;
  const int w = tid >> 6, l = tid & 63;

  // nt-major XCD swizzle: 1376 blocks = 8 XCD x 172; bijective.
  const int bid = blockIdx.x;
  const int xcd = bid & 7, ii = bid >> 3;   // ii in [0,172)
  const int nt = ii >> 1;                   // 0..85  (weight panel, slow)
  const int mt = xcd * 2 + (ii & 1);        // 0..15  (X panel, 2 per XCD)
  const int m0 = mt * 256, n0 = nt * 128;

  const int p = w & 7;
  const bool isGate = (w < 8);
  const int wr = p >> 1, wc = p & 1;

  // ---- staging: 32 1KB-units, 2 per wave (round-4 verified map) ----
  const int lrow = l >> 2;                              // 0..15
  const int kc8 = (((l & 3) ^ ((l >> 3) & 3)) << 3);    // elem col 0,8,16,24
  const unsigned short* gsrc0;
  const unsigned short* gsrc1;
  int ldst0;
  if (w < 8) {          // A units 2w, 2w+1 (rows m0+32w .. +31)
    gsrc0 = X + (size_t)(m0 + 32 * w + lrow) * K + kc8;
    gsrc1 = X + (size_t)(m0 + 32 * w + 16 + lrow) * K + kc8;
    ldst0 = 2 * w * 1024;
  } else if (w < 12) {  // B1 units
    gsrc0 = W1 + (size_t)(n0 + 32 * (w - 8) + lrow) * K + kc8;
    gsrc1 = W1 + (size_t)(n0 + 32 * (w - 8) + 16 + lrow) * K + kc8;
    ldst0 = 16384 + (w - 8) * 2048;
  } else {              // B2 units
    gsrc0 = W2 + (size_t)(n0 + 32 * (w - 12) + lrow) * K + kc8;
    gsrc1 = W2 + (size_t)(n0 + 32 * (w - 12) + 16 + lrow) * K + kc8;
    ldst0 = 24576 + (w - 12) * 2048;
  }

  // ---- read bases ----
  const int roff = (((l >> 4) ^ ((l >> 1) & 3)) << 4);
  const char* rdA = ldsb + (wr * 64 + (l & 15)) * 64 + roff;
  const char* rdB = ldsb + 16384 + (isGate ? 0 : 8192) +
                    (wc * 64 + (l & 15)) * 64 + roff;

  f32x4 acc[4][4] = {};

#define TILE_BODY(bo) {                                                        \
  bf16x8 a[4], b[4];                                                           \
  _Pragma("unroll") for (int m = 0; m < 4; ++m)                                \
    a[m] = *(const bf16x8*)(rdA + (bo) + m * 1024);                            \
  _Pragma("unroll") for (int n = 0; n < 4; ++n)                                \
    b[n] = *(const bf16x8*)(rdB + (bo) + n * 1024);                            \
  __builtin_amdgcn_s_setprio(1);                                               \
  _Pragma("unroll") for (int m = 0; m < 4; ++m)                                \
    _Pragma("unroll") for (int n = 0; n < 4; ++n)                              \
      acc[m][n] = __builtin_amdgcn_mfma_f32_16x16x32_bf16(a[m], b[n], acc[m][n], 0, 0, 0); \
  __builtin_amdgcn_s_setprio(0); }

  // prologue: stage tiles 0,1,2 into bufs 0,1,2
  gload16(gsrc0, ldsb + ldst0);               gload16(gsrc1, ldsb + ldst0 + 1024);
  gload16(gsrc0 + 32, ldsb + 32768 + ldst0);  gload16(gsrc1 + 32, ldsb + 32768 + ldst0 + 1024);
  gload16(gsrc0 + 64, ldsb + 65536 + ldst0);  gload16(gsrc1 + 64, ldsb + 65536 + ldst0 + 1024);
  const unsigned short* pg0 = gsrc0 + 96;     // tile t+3 cursor
  const unsigned short* pg1 = gsrc1 + 96;
  WAITV(2);
  barrier_nodrain();

  int bo_r0 = 0, bo_r1 = 32768;          // read bufs (tiles t, t+1)
  int bo_s0 = 98304, bo_s1 = 131072;     // stage bufs (tiles t+3, t+4)
  for (int t = 0; t + 4 < NK; t += 2) {  // full pairs
    gload16(pg0, ldsb + bo_s0 + ldst0);
    gload16(pg1, ldsb + bo_s0 + ldst0 + 1024);
    gload16(pg0 + 32, ldsb + bo_s1 + ldst0);
    gload16(pg1 + 32, ldsb + bo_s1 + ldst0 + 1024);
    pg0 += 64; pg1 += 64;
    TILE_BODY(bo_r0);
    __builtin_amdgcn_sched_barrier(0);   // cap live ranges (anti-spill)
    TILE_BODY(bo_r1);
    WAITV(2); barrier_nodrain();
    bo_r0 = wrap5(bo_r0 + 65536); bo_r1 = wrap5(bo_r1 + 65536);
    bo_s0 = wrap5(bo_s0 + 65536); bo_s1 = wrap5(bo_s1 + 65536);
  }
  // pair (NK-4, NK-3): stage tile NK-1 only
  gload16(pg0, ldsb + bo_s0 + ldst0);
  gload16(pg1, ldsb + bo_s0 + ldst0 + 1024);
  TILE_BODY(bo_r0);
  __builtin_amdgcn_sched_barrier(0);
  TILE_BODY(bo_r1);
  WAITV(0); barrier_nodrain();
  bo_r0 = wrap5(bo_r0 + 65536); bo_r1 = wrap5(bo_r1 + 65536);
  // pair (NK-2, NK-1): reads only
  TILE_BODY(bo_r0);
  __builtin_amdgcn_sched_barrier(0);
  TILE_BODY(bo_r1);
#undef TILE_BODY

  // ---- epilogue: pairwise f32 exchange (m-split), balanced stores ----
  barrier_nodrain();  // staging LDS now dead for ALL waves
  char* xch = ldsb + p * 16384 + (isGate ? 0 : 8192);
#pragma unroll
  for (int m2 = 0; m2 < 2; ++m2)
#pragma unroll
    for (int n = 0; n < 4; ++n) {
      const int m = isGate ? (m2 + 2) : m2;
      *(f32x4*)(xch + ((m2 * 4 + n) * 64 + l) * 16) = acc[m][n];
    }
  barrier_nodrain();
  const char* oxch = ldsb + p * 16384 + (isGate ? 8192 : 0);
  const int er = (l >> 4) * 4, ec = l & 15;
#pragma unroll
  for (int m2 = 0; m2 < 2; ++m2)
#pragma unroll
    for (int n = 0; n < 4; ++n) {
      const int mk = isGate ? m2 : (m2 + 2);   // rows this wave stores
      f32x4 other = *(const f32x4*)(oxch + ((m2 * 4 + n) * 64 + l) * 16);
#pragma unroll
      for (int j = 0; j < 4; ++j) {
        const float g_ = isGate ? acc[mk][n][j] : other[j];
        const float u_ = isGate ? other[j] : acc[mk][n][j];
        const float s = fast_silu(g_);
        const int row = m0 + wr * 64 + mk * 16 + er + j;
        const int col = n0 + wc * 64 + n * 16 + ec;
        H[(size_t)row * N + col] = f32_to_bf16(s * u_);
      }
    }
}

// ---------------------------------------------------------------------------
// Output GEMM. BM=BN=256, BK=32, 16 waves (4M x 4N), per-wave 64x64.
// 5 LDS bufs x 32KB (A 16K | B 16K) = 160 KiB, pairwise pipeline.
// nt-major XCD swizzle. H x W3^T -> Out f32.
// ---------------------------------------------------------------------------
__global__ void __launch_bounds__(1024, 4) k_gemm_out(
    const unsigned short* __restrict__ Hm,
    const unsigned short* __restrict__ W3,
    float* __restrict__ Out) {
  constexpr int K = 11008, N = 4096, NK = K / 32;   // NK = 344 (even)
  __shared__ char ldsb[163840];

  const int tid = threadIdx.x;
  const int w = tid >> 6, l = tid & 63;

  const int bid = blockIdx.x;
  const int xcd = bid & 7, ii = bid >> 3;   // ii in [0,32)
  const int nt = ii >> 1;                   // 0..15
  const int mt = xcd * 2 + (ii & 1);        // 0..15
  const int m0 = mt * 256, n0 = nt * 256;

  const int wr = w >> 2, wc = w & 3;

  const int lrow = l >> 2;
  const int kc8 = (((l & 3) ^ ((l >> 3) & 3)) << 3);
  const unsigned short* gsrc0;
  const unsigned short* gsrc1;
  int ldst0;
  if (w < 8) {          // A units
    gsrc0 = Hm + (size_t)(m0 + 32 * w + lrow) * K + kc8;
    gsrc1 = Hm + (size_t)(m0 + 32 * w + 16 + lrow) * K + kc8;
    ldst0 = 2 * w * 1024;
  } else {              // B units
    gsrc0 = W3 + (size_t)(n0 + 32 * (w - 8) + lrow) * K + kc8;
    gsrc1 = W3 + (size_t)(n0 + 32 * (w - 8) + 16 + lrow) * K + kc8;
    ldst0 = 16384 + (w - 8) * 2048;
  }

  const int roff = (((l >> 4) ^ ((l >> 1) & 3)) << 4);
  const char* rdA = ldsb + (wr * 64 + (l & 15)) * 64 + roff;
  const char* rdB = ldsb + 16384 + (wc * 64 + (l & 15)) * 64 + roff;

  f32x4 acc[4][4] = {};

#define TILE_BODY(bo) {                                                        \
  bf16x8 a[4], b[4];                                                           \
  _Pragma("unroll") for (int m = 0; m < 4; ++m)                                \
    a[m] = *(const bf16x8*)(rdA + (bo) + m * 1024);                            \
  _Pragma("unroll") for (int n = 0; n < 4; ++n)                                \
    b[n] = *(const bf16x8*)(rdB + (bo) + n * 1024);                            \
  __builtin_amdgcn_s_setprio(1);                                               \
  _Pragma("unroll") for (int m = 0; m < 4; ++m)                                \
    _Pragma("unroll") for (int n = 0; n < 4; ++n)                              \
      acc[m][n] = __builtin_amdgcn_mfma_f32_16x16x32_bf16(a[m], b[n], acc[m][n], 0, 0, 0); \
  __builtin_amdgcn_s_setprio(0); }

  gload16(gsrc0, ldsb + ldst0);               gload16(gsrc1, ldsb + ldst0 + 1024);
  gload16(gsrc0 + 32, ldsb + 32768 + ldst0);  gload16(gsrc1 + 32, ldsb + 32768 + ldst0 + 1024);
  gload16(gsrc0 + 64, ldsb + 65536 + ldst0);  gload16(gsrc1 + 64, ldsb + 65536 + ldst0 + 1024);
  const unsigned short* pg0 = gsrc0 + 96;
  const unsigned short* pg1 = gsrc1 + 96;
  WAITV(2);
  barrier_nodrain();

  int bo_r0 = 0, bo_r1 = 32768;
  int bo_s0 = 98304, bo_s1 = 131072;
  for (int t = 0; t + 4 < NK; t += 2) {
    gload16(pg0, ldsb + bo_s0 + ldst0);
    gload16(pg1, ldsb + bo_s0 + ldst0 + 1024);
    gload16(pg0 + 32, ldsb + bo_s1 + ldst0);
    gload16(pg1 + 32, ldsb + bo_s1 + ldst0 + 1024);
    pg0 += 64; pg1 += 64;
    TILE_BODY(bo_r0);
    __builtin_amdgcn_sched_barrier(0);
    TILE_BODY(bo_r1);
    WAITV(2); barrier_nodrain();
    bo_r0 = wrap5(bo_r0 + 65536); bo_r1 = wrap5(bo_r1 + 65536);
    bo_s0 = wrap5(bo_s0 + 65536); bo_s1 = wrap5(bo_s1 + 65536);
  }
  gload16(pg0, ldsb + bo_s0 + ldst0);
  gload16(pg1, ldsb + bo_s0 + ldst0 + 1024);
  TILE_BODY(bo_r0);
  __builtin_amdgcn_sched_barrier(0);
  TILE_BODY(bo_r1);
  WAITV(0); barrier_nodrain();
  bo_r0 = wrap5(bo_r0 + 65536); bo_r1 = wrap5(bo_r1 + 65536);
  TILE_BODY(bo_r0);
  __builtin_amdgcn_sched_barrier(0);
  TILE_BODY(bo_r1);
#undef TILE_BODY

  const int er = (l >> 4) * 4, ec = l & 15;
#pragma unroll
  for (int m = 0; m < 4; ++m)
#pragma unroll
    for (int n = 0; n < 4; ++n) {
      const int row = m0 + wr * 64 + m * 16 + er;
      const int col = n0 + wc * 64 + n * 16 + ec;
      float* ptr = Out + (size_t)row * N + col;
#pragma unroll
      for (int j = 0; j < 4; ++j) ptr[(size_t)j * N] = acc[m][n][j];
    }
}

// ---------------------------------------------------------------------------
extern "C" void kernel_launch(void* const* d_in, const int* in_sizes, int n_in,
                              void* d_out, int out_size, void* d_ws, size_t ws_size,
                              hipStream_t stream) {
  const float* x  = (const float*)d_in[0];   // [2,2048,4096] -> [4096][4096]
  const float* w1 = (const float*)d_in[1];   // [11008,4096]
  const float* w2 = (const float*)d_in[2];   // [11008,4096]
  const float* w3 = (const float*)d_in[3];   // [4096,11008]
  float* out = (float*)d_out;

  char* ws = (char*)d_ws;
  unsigned short* xb  = (unsigned short*)(ws);                // 32 MiB
  unsigned short* w1b = (unsigned short*)(ws + 33554432);     // 86 MiB
  unsigned short* w2b = (unsigned short*)(ws + 123731968);    // 86 MiB
  unsigned short* hb  = (unsigned short*)(ws + 213909504);    // 86 MiB
  unsigned short* w3b = w1b;  // reuse after gemm1 (stream-ordered)

  const int NW = 11008 * 4096 / 4;
  k_f32_to_bf16<<<16384, 256, 0, stream>>>(x, xb, 4096 * 4096 / 4);
  k_dequant_nf4_2<<<2 * (NW / 256), 256, 0, stream>>>(w1, w2, w1b, w2b, NW);

  // gate/up + SwiGLU -> h  (M=4096, N=11008, K=4096)
  k_gemm_dual_swiglu<<<1376, 1024, 0, stream>>>(xb, w1b, w2b, hb);

  k_dequant_nf4<<<NW / 256, 256, 0, stream>>>(w3, w3b, NW);

  // out = h . w3^T  (M=4096, N=4096, K=11008)
  k_gemm_out<<<256, 1024, 0, stream>>>(hb, w3b, out);
}

// Round 12
// 1210.495 us; speedup vs baseline: 7.1733x; 1.0333x over previous
//
#include <hip/hip_runtime.h>
#include <math.h>

typedef __attribute__((ext_vector_type(4))) float f32x4;
typedef __attribute__((ext_vector_type(8))) short bf16x8;

#define DI __device__ __forceinline__

DI unsigned short f32_to_bf16(float f) {
  unsigned int u = __float_as_uint(f);
  u += 0x7FFFu + ((u >> 16) & 1u);   // round-to-nearest-even
  return (unsigned short)(u >> 16);
}

static constexpr float kCode[16] = {
    -1.0f, -0.6961928009986877f, -0.5250730514526367f, -0.39491748809814453f,
    -0.28444138169288635f, -0.18477343022823334f, -0.09105003625154495f, 0.0f,
    0.07958029955625534f, 0.16093020141124725f, 0.24611230194568634f,
    0.33791524171829224f, 0.44070982933044434f, 0.5626170039176941f,
    0.7229568362236023f, 1.0f};

// ---------------------------------------------------------------------------
// NF4 quant-dequant (block=64): 16 lanes/block, float4/lane. Division-free.
// ---------------------------------------------------------------------------
DI void dequant_body(const float* __restrict__ in, unsigned short* __restrict__ out, int i) {
  f32x4 v = reinterpret_cast<const f32x4*>(in)[i];
  float am = fmaxf(fmaxf(fabsf(v.x), fabsf(v.y)), fmaxf(fabsf(v.z), fabsf(v.w)));
  am = fmaxf(am, __shfl_xor(am, 1));
  am = fmaxf(am, __shfl_xor(am, 2));
  am = fmaxf(am, __shfl_xor(am, 4));
  am = fmaxf(am, __shfl_xor(am, 8));
  const float scale = (am == 0.0f) ? 1.0f : am;
  float sb[15];
#pragma unroll
  for (int b = 0; b < 15; ++b)
    sb[b] = (0.5f * (kCode[b] + kCode[b + 1])) * scale;
  unsigned short o[4];
#pragma unroll
  for (int j = 0; j < 4; ++j) {
    const float vj = ((const float*)&v)[j];
    int idx = 0;
#pragma unroll
    for (int b = 0; b < 15; ++b)
      idx += (vj > sb[b]) ? 1 : 0;
    o[j] = f32_to_bf16(kCode[idx] * am);
  }
  reinterpret_cast<ushort4*>(out)[i] = make_ushort4(o[0], o[1], o[2], o[3]);
}

__global__ void __launch_bounds__(256) k_dequant_nf4(
    const float* __restrict__ in, unsigned short* __restrict__ out, int n4) {
  int i = blockIdx.x * 256 + threadIdx.x;
  if (i >= n4) return;
  dequant_body(in, out, i);
}

// merged aux: x f32->bf16 convert, then w1 and w2 NF4 dequant, one launch.
// range boundaries are multiples of 256 -> branch is block-uniform.
__global__ void __launch_bounds__(256) k_aux_all(
    const float* __restrict__ x, unsigned short* __restrict__ xb, int n4x,
    const float* __restrict__ w1, unsigned short* __restrict__ w1b,
    const float* __restrict__ w2, unsigned short* __restrict__ w2b, int n4w) {
  int i = blockIdx.x * 256 + threadIdx.x;
  if (i < n4x) {
    f32x4 v = reinterpret_cast<const f32x4*>(x)[i];
    reinterpret_cast<ushort4*>(xb)[i] =
        make_ushort4(f32_to_bf16(v.x), f32_to_bf16(v.y), f32_to_bf16(v.z), f32_to_bf16(v.w));
  } else if (i < n4x + n4w) {
    dequant_body(w1, w1b, i - n4x);
  } else {
    dequant_body(w2, w2b, i - n4x - n4w);
  }
}

// ---------------------------------------------------------------------------
// GEMM helpers. BK=32, LDS rows = 64B. Element (r,k) at byte
//   r*64 + (((k>>3) ^ ((r>>1)&3))<<4) + (k&7)*2     (round-4 verified)
// Staging: global_load_lds linear; lane l of 1KB unit covers row 16u+(l>>2),
// k-chunk (l&3)^((l>>3)&3). Read: (rowbase+(l&15))*64 + ((l>>4)^((l>>1)&3))<<4
// -> conflict-free (SQ_LDS_BANK_CONFLICT == 0, rounds 4/5/8/9/11).
// ---------------------------------------------------------------------------
DI void gload16(const void* g, void* l) {
  __builtin_amdgcn_global_load_lds(
      (const __attribute__((address_space(1))) void*)g,
      (__attribute__((address_space(3))) void*)l, 16, 0, 0);
}

DI void barrier_nodrain() {
  asm volatile("" ::: "memory");
  __builtin_amdgcn_s_barrier();
  asm volatile("" ::: "memory");
}

#define WAITV(N) asm volatile("s_waitcnt vmcnt(" #N ")" ::: "memory")

DI float fast_silu(float g) {
  const float e = __builtin_amdgcn_exp2f(g * -1.442695041f);
  return g * __builtin_amdgcn_rcpf(1.0f + e);
}

// ---------------------------------------------------------------------------
// Fused dual GEMM + SwiGLU. BM=256, BN=128, BK=32, 16 waves (4/SIMD):
// waves 0-7 gate (B1), 8-15 up (B2); pair p = w&7 owns 64x64 at
// (wr=p>>1, wc=p&1). 4 LDS bufs x 32KB (A 16K | B1 8K | B2 8K),
// prefetch distance 3, counted vmcnt(4), hoisted wait-ladder,
// pointer-increment staging. nt-major XCD swizzle. No setprio (m190).
// ---------------------------------------------------------------------------
__global__ void __launch_bounds__(1024, 4) k_gemm_dual_swiglu(
    const unsigned short* __restrict__ X,
    const unsigned short* __restrict__ W1,
    const unsigned short* __restrict__ W2,
    unsigned short* __restrict__ H) {
  constexpr int K = 4096, N = 11008, NK = K / 32;
  __shared__ char ldsb[131072];

  const int tid = threadIdx.x;
  const int w = tid >> 6, l = tid & 63;

  // nt-major XCD swizzle: 1376 blocks = 8 XCD x 172; bijective.
  const int bid = blockIdx.x;
  const int xcd = bid & 7, ii = bid >> 3;   // ii in [0,172)
  const int nt = ii >> 1;                   // 0..85  (weight panel, slow)
  const int mt = xcd * 2 + (ii & 1);        // 0..15  (X panel, 2 per XCD)
  const int m0 = mt * 256, n0 = nt * 128;

  const int p = w & 7;
  const bool isGate = (w < 8);
  const int wr = p >> 1, wc = p & 1;

  // ---- staging: 32 1KB-units, 2 per wave (round-4 verified map) ----
  const int lrow = l >> 2;                              // 0..15
  const int kc8 = (((l & 3) ^ ((l >> 3) & 3)) << 3);    // elem col 0,8,16,24
  const unsigned short* gsrc0;
  const unsigned short* gsrc1;
  int ldst0;
  if (w < 8) {          // A units 2w, 2w+1 (rows m0+32w .. +31)
    gsrc0 = X + (size_t)(m0 + 32 * w + lrow) * K + kc8;
    gsrc1 = X + (size_t)(m0 + 32 * w + 16 + lrow) * K + kc8;
    ldst0 = 2 * w * 1024;
  } else if (w < 12) {  // B1 units
    gsrc0 = W1 + (size_t)(n0 + 32 * (w - 8) + lrow) * K + kc8;
    gsrc1 = W1 + (size_t)(n0 + 32 * (w - 8) + 16 + lrow) * K + kc8;
    ldst0 = 16384 + (w - 8) * 2048;
  } else {              // B2 units
    gsrc0 = W2 + (size_t)(n0 + 32 * (w - 12) + lrow) * K + kc8;
    gsrc1 = W2 + (size_t)(n0 + 32 * (w - 12) + 16 + lrow) * K + kc8;
    ldst0 = 24576 + (w - 12) * 2048;
  }

  // ---- read bases ----
  const int roff = (((l >> 4) ^ ((l >> 1) & 3)) << 4);
  const char* rdA = ldsb + (wr * 64 + (l & 15)) * 64 + roff;
  const char* rdB = ldsb + 16384 + (isGate ? 0 : 8192) +
                    (wc * 64 + (l & 15)) * 64 + roff;

  f32x4 acc[4][4] = {};

#define TILE_BODY(bo) {                                                        \
  bf16x8 a[4], b[4];                                                           \
  _Pragma("unroll") for (int m = 0; m < 4; ++m)                                \
    a[m] = *(const bf16x8*)(rdA + (bo) + m * 1024);                            \
  _Pragma("unroll") for (int n = 0; n < 4; ++n)                                \
    b[n] = *(const bf16x8*)(rdB + (bo) + n * 1024);                            \
  _Pragma("unroll") for (int m = 0; m < 4; ++m)                                \
    _Pragma("unroll") for (int n = 0; n < 4; ++n)                              \
      acc[m][n] = __builtin_amdgcn_mfma_f32_16x16x32_bf16(a[m], b[n], acc[m][n], 0, 0, 0); }

  // prologue: stage tiles 0,1,2
  gload16(gsrc0, ldsb + ldst0);               gload16(gsrc1, ldsb + ldst0 + 1024);
  gload16(gsrc0 + 32, ldsb + 32768 + ldst0);  gload16(gsrc1 + 32, ldsb + 32768 + ldst0 + 1024);
  gload16(gsrc0 + 64, ldsb + 65536 + ldst0);  gload16(gsrc1 + 64, ldsb + 65536 + ldst0 + 1024);
  const unsigned short* pg0 = gsrc0 + 96;     // tile t+3 cursor
  const unsigned short* pg1 = gsrc1 + 96;
  WAITV(4);
  barrier_nodrain();

  int t = 0;
  for (; t + 3 < NK; ++t) {              // branchless main loop
    const int bo = (t & 3) << 15;
    const int bs = ((t + 3) & 3) << 15;
    gload16(pg0, ldsb + bs + ldst0);
    gload16(pg1, ldsb + bs + ldst0 + 1024);
    pg0 += 32; pg1 += 32;
    TILE_BODY(bo);
    WAITV(4); barrier_nodrain();
  }
  // tail: t = NK-3, NK-2, NK-1 (no staging)
  TILE_BODY((t & 3) << 15); WAITV(2); barrier_nodrain(); ++t;
  TILE_BODY((t & 3) << 15); WAITV(0); barrier_nodrain(); ++t;
  TILE_BODY((t & 3) << 15);
#undef TILE_BODY

  // ---- epilogue: pairwise f32 exchange (m-split), balanced stores ----
  barrier_nodrain();  // staging LDS now dead for ALL waves
  char* xch = ldsb + p * 16384 + (isGate ? 0 : 8192);
  // gate writes its m=2,3 frags; up writes its m=0,1 frags
#pragma unroll
  for (int m2 = 0; m2 < 2; ++m2)
#pragma unroll
    for (int n = 0; n < 4; ++n) {
      const int m = isGate ? (m2 + 2) : m2;
      *(f32x4*)(xch + ((m2 * 4 + n) * 64 + l) * 16) = acc[m][n];
    }
  barrier_nodrain();
  const char* oxch = ldsb + p * 16384 + (isGate ? 8192 : 0);
  const int er = (l >> 4) * 4, ec = l & 15;
#pragma unroll
  for (int m2 = 0; m2 < 2; ++m2)
#pragma unroll
    for (int n = 0; n < 4; ++n) {
      const int mk = isGate ? m2 : (m2 + 2);   // rows this wave stores
      f32x4 other = *(const f32x4*)(oxch + ((m2 * 4 + n) * 64 + l) * 16);
#pragma unroll
      for (int j = 0; j < 4; ++j) {
        const float g_ = isGate ? acc[mk][n][j] : other[j];
        const float u_ = isGate ? other[j] : acc[mk][n][j];
        const float s = fast_silu(g_);
        const int row = m0 + wr * 64 + mk * 16 + er + j;
        const int col = n0 + wc * 64 + n * 16 + ec;
        H[(size_t)row * N + col] = f32_to_bf16(s * u_);
      }
    }
}

// ---------------------------------------------------------------------------
// Output GEMM. BM=BN=256, BK=32, 16 waves (4M x 4N), per-wave 64x64.
// 4 LDS bufs x 32KB (A 16K | B 16K), prefetch 3, hoisted ladder,
// pointer-increment staging. nt-major XCD swizzle. No setprio.
// H:[4096][11008] bf16, W3:[4096][11008] bf16 -> Out:[4096][4096] f32
// ---------------------------------------------------------------------------
__global__ void __launch_bounds__(1024, 4) k_gemm_out(
    const unsigned short* __restrict__ Hm,
    const unsigned short* __restrict__ W3,
    float* __restrict__ Out) {
  constexpr int K = 11008, N = 4096, NK = K / 32;   // NK = 344
  __shared__ char ldsb[131072];

  const int tid = threadIdx.x;
  const int w = tid >> 6, l = tid & 63;

  const int bid = blockIdx.x;
  const int xcd = bid & 7, ii = bid >> 3;   // ii in [0,32)
  const int nt = ii >> 1;                   // 0..15
  const int mt = xcd * 2 + (ii & 1);        // 0..15
  const int m0 = mt * 256, n0 = nt * 256;

  const int wr = w >> 2, wc = w & 3;

  const int lrow = l >> 2;
  const int kc8 = (((l & 3) ^ ((l >> 3) & 3)) << 3);
  const unsigned short* gsrc0;
  const unsigned short* gsrc1;
  int ldst0;
  if (w < 8) {          // A units
    gsrc0 = Hm + (size_t)(m0 + 32 * w + lrow) * K + kc8;
    gsrc1 = Hm + (size_t)(m0 + 32 * w + 16 + lrow) * K + kc8;
    ldst0 = 2 * w * 1024;
  } else {              // B units
    gsrc0 = W3 + (size_t)(n0 + 32 * (w - 8) + lrow) * K + kc8;
    gsrc1 = W3 + (size_t)(n0 + 32 * (w - 8) + 16 + lrow) * K + kc8;
    ldst0 = 16384 + (w - 8) * 2048;
  }

  const int roff = (((l >> 4) ^ ((l >> 1) & 3)) << 4);
  const char* rdA = ldsb + (wr * 64 + (l & 15)) * 64 + roff;
  const char* rdB = ldsb + 16384 + (wc * 64 + (l & 15)) * 64 + roff;

  f32x4 acc[4][4] = {};

#define TILE_BODY(bo) {                                                        \
  bf16x8 a[4], b[4];                                                           \
  _Pragma("unroll") for (int m = 0; m < 4; ++m)                                \
    a[m] = *(const bf16x8*)(rdA + (bo) + m * 1024);                            \
  _Pragma("unroll") for (int n = 0; n < 4; ++n)                                \
    b[n] = *(const bf16x8*)(rdB + (bo) + n * 1024);                            \
  _Pragma("unroll") for (int m = 0; m < 4; ++m)                                \
    _Pragma("unroll") for (int n = 0; n < 4; ++n)                              \
      acc[m][n] = __builtin_amdgcn_mfma_f32_16x16x32_bf16(a[m], b[n], acc[m][n], 0, 0, 0); }

  gload16(gsrc0, ldsb + ldst0);               gload16(gsrc1, ldsb + ldst0 + 1024);
  gload16(gsrc0 + 32, ldsb + 32768 + ldst0);  gload16(gsrc1 + 32, ldsb + 32768 + ldst0 + 1024);
  gload16(gsrc0 + 64, ldsb + 65536 + ldst0);  gload16(gsrc1 + 64, ldsb + 65536 + ldst0 + 1024);
  const unsigned short* pg0 = gsrc0 + 96;
  const unsigned short* pg1 = gsrc1 + 96;
  WAITV(4);
  barrier_nodrain();

  int t = 0;
  for (; t + 3 < NK; ++t) {
    const int bo = (t & 3) << 15;
    const int bs = ((t + 3) & 3) << 15;
    gload16(pg0, ldsb + bs + ldst0);
    gload16(pg1, ldsb + bs + ldst0 + 1024);
    pg0 += 32; pg1 += 32;
    TILE_BODY(bo);
    WAITV(4); barrier_nodrain();
  }
  TILE_BODY((t & 3) << 15); WAITV(2); barrier_nodrain(); ++t;
  TILE_BODY((t & 3) << 15); WAITV(0); barrier_nodrain(); ++t;
  TILE_BODY((t & 3) << 15);
#undef TILE_BODY

  const int er = (l >> 4) * 4, ec = l & 15;
#pragma unroll
  for (int m = 0; m < 4; ++m)
#pragma unroll
    for (int n = 0; n < 4; ++n) {
      const int row = m0 + wr * 64 + m * 16 + er;
      const int col = n0 + wc * 64 + n * 16 + ec;
      float* ptr = Out + (size_t)row * N + col;
#pragma unroll
      for (int j = 0; j < 4; ++j) ptr[(size_t)j * N] = acc[m][n][j];
    }
}

// ---------------------------------------------------------------------------
extern "C" void kernel_launch(void* const* d_in, const int* in_sizes, int n_in,
                              void* d_out, int out_size, void* d_ws, size_t ws_size,
                              hipStream_t stream) {
  const float* x  = (const float*)d_in[0];   // [2,2048,4096] -> [4096][4096]
  const float* w1 = (const float*)d_in[1];   // [11008,4096]
  const float* w2 = (const float*)d_in[2];   // [11008,4096]
  const float* w3 = (const float*)d_in[3];   // [4096,11008]
  float* out = (float*)d_out;

  char* ws = (char*)d_ws;
  unsigned short* xb  = (unsigned short*)(ws);                // 32 MiB
  unsigned short* w1b = (unsigned short*)(ws + 33554432);     // 86 MiB
  unsigned short* w2b = (unsigned short*)(ws + 123731968);    // 86 MiB
  unsigned short* hb  = (unsigned short*)(ws + 213909504);    // 86 MiB
  unsigned short* w3b = w1b;  // reuse after gemm1 (stream-ordered)

  const int N4X = 4096 * 4096 / 4;           // 4,194,304  (16384 blocks)
  const int NW  = 11008 * 4096 / 4;          // 11,272,192 (44032 blocks)
  const int AUX_BLOCKS = (N4X + 2 * NW) / 256;
  k_aux_all<<<AUX_BLOCKS, 256, 0, stream>>>(x, xb, N4X, w1, w1b, w2, w2b, NW);

  // gate/up + SwiGLU -> h  (M=4096, N=11008, K=4096)
  k_gemm_dual_swiglu<<<1376, 1024, 0, stream>>>(xb, w1b, w2b, hb);

  k_dequant_nf4<<<NW / 256, 256, 0, stream>>>(w3, w3b, NW);

  // out = h . w3^T  (M=4096, N=4096, K=11008)
  k_gemm_out<<<256, 1024, 0, stream>>>(hb, w3b, out);
}